// Round 13
// baseline (491.881 us; speedup 1.0000x reference)
//
#include <hip/hip_runtime.h>
#include <hip/hip_bf16.h>

typedef unsigned short u16;
typedef unsigned int u32;
typedef __attribute__((ext_vector_type(8))) short short8;   // bf16x8 MFMA frag (4 VGPR)
typedef __attribute__((ext_vector_type(4))) float float4v;  // fp32x4 acc
typedef __attribute__((ext_vector_type(4))) unsigned int uint4v; // 16B vector
typedef __attribute__((ext_vector_type(2))) unsigned int uint2v; // 8B vector
typedef __attribute__((ext_vector_type(2))) float float2v;  // 8B float pair

__device__ __forceinline__ u16 f2bf(float f) {
    union { float f; unsigned int u; } v; v.f = f;
    unsigned int r = v.u + 0x7fffu + ((v.u >> 16) & 1u);  // RNE
    return (u16)(r >> 16);
}

// packed fp32x2 -> bf16x2 (no builtin on gfx950; T12 recipe)
__device__ __forceinline__ u32 cvtpk(float lo, float hi) {
    u32 r;
    asm("v_cvt_pk_bf16_f32 %0, %1, %2" : "=v"(r) : "v"(lo), "v"(hi));
    return r;
}
// bf16 pair unpack: element 0 is low u16, element 1 is high u16
__device__ __forceinline__ float bflo(u32 u) {
    union { u32 u; float f; } v; v.u = u << 16; return v.f;
}
__device__ __forceinline__ float bfhi(u32 u) {
    union { u32 u; float f; } v; v.u = u & 0xffff0000u; return v.f;
}

// async 16B global -> LDS (lane i lands at ldsbase + i*16)
__device__ __forceinline__ void gld_lds16(const u16* g, u16* l) {
    __builtin_amdgcn_global_load_lds(
        (const __attribute__((address_space(1))) u32*)g,
        (__attribute__((address_space(3))) u32*)l, 16, 0, 0);
}

// ---------------------------------------------------------------------------
// x: fp32 [8192*1024] -> bf16. 8 elements/thread.
// ---------------------------------------------------------------------------
__global__ __launch_bounds__(256) void convert_x(
    const float* __restrict__ x, u16* __restrict__ xb) {
    int i = (blockIdx.x * 256 + threadIdx.x) * 8;
    float4v a = *(const float4v*)&x[i];
    float4v b = *(const float4v*)&x[i + 4];
    u16 tmp[8] __attribute__((aligned(16)));
#pragma unroll
    for (int j = 0; j < 4; ++j) { tmp[j] = f2bf(a[j]); tmp[4 + j] = f2bf(b[j]); }
    *(uint4v*)&xb[i] = *(uint4v*)tmp;
}

// ---------------------------------------------------------------------------
// Weight transpose+convert: W fp32 [1024][1024] (K x N) -> Wt bf16 (N x K).
// ---------------------------------------------------------------------------
__global__ __launch_bounds__(256) void transpose_w(
    const float* __restrict__ w0, const float* __restrict__ w1,
    const float* __restrict__ w2, const float* __restrict__ w3,
    u16* __restrict__ o0, u16* __restrict__ o1,
    u16* __restrict__ o2, u16* __restrict__ o3) {
    __shared__ u16 t[32][33];
    int z = blockIdx.z;
    const float* w = (z == 0) ? w0 : (z == 1) ? w1 : (z == 2) ? w2 : w3;
    u16* o         = (z == 0) ? o0 : (z == 1) ? o1 : (z == 2) ? o2 : o3;
    int bx = blockIdx.x * 32;   // input col (n)
    int by = blockIdx.y * 32;   // input row (k)
    int x = threadIdx.x, y = threadIdx.y;   // block (32,8)
#pragma unroll
    for (int i = 0; i < 4; ++i)
        t[y + i * 8][x] = f2bf(w[(size_t)(by + y + i * 8) * 1024 + bx + x]);
    __syncthreads();
#pragma unroll
    for (int i = 0; i < 4; ++i)
        o[(size_t)(bx + y + i * 8) * 1024 + by + x] = t[x][y + i * 8];
}

// ---------------------------------------------------------------------------
// Fused QKV GEMM: [8192 x 1024] @ [1024 x 3072] with wtq|wtk|wtv contiguous
// as one Bt [3072][1024].  R18: grid 1536 blocks -> 6 blocks/CU cap (~3-4
// resident) vs the 512-block per-GEMM grid's hard 2/CU -- the R17 counter
// analysis showed the QKV GEMMs were grid-capped on latency hiding
// (~1690 cyc/iter vs m97's ~940 at 3 blocks/CU).  A-panels get 3x more L2
// reuse (24 n-blocks/row-panel, same XCD via bid%64 mapping).  Epilogue
// branches per-block-uniformly on n-segment: Q (scaled) | K | V(transposed).
// ---------------------------------------------------------------------------
__global__ __launch_bounds__(256) void gemm_qkv(
    const u16* __restrict__ A, const u16* __restrict__ Bt,
    u16* __restrict__ qo, u16* __restrict__ ko, u16* __restrict__ vo,
    float qscale) {
    __shared__ __attribute__((aligned(16))) u16 As[128 * 32];
    __shared__ __attribute__((aligned(16))) u16 Bs[128 * 32];
    const int tid = threadIdx.x;
    const int bid = blockIdx.x;
    const int m0 = (bid & 63) * 128;          // row panel: XCD-resident
    const int n0 = (bid >> 6) * 128;          // col panel 0..2944
    const int wid = tid >> 6;
    const int lane = tid & 63;
    const int ln = lane & 15, kq = lane >> 4;
    const int wm = (wid >> 1) * 64, wn = (wid & 1) * 64;
    const int K = 1024;

    float4v acc[4][4] = {};
    for (int k0 = 0; k0 < K; k0 += 32) {
#pragma unroll
        for (int i = 0; i < 2; ++i) {
            int chunk = tid + i * 256;          // 16B chunk id, 0..511
            int row = chunk >> 2, cg = chunk & 3;
            u16* lA = &As[(size_t)(i * 256 + wid * 64) * 8];
            u16* lB = &Bs[(size_t)(i * 256 + wid * 64) * 8];
            gld_lds16(&A[(size_t)(m0 + row) * K + k0 + cg * 8], lA);
            gld_lds16(&Bt[(size_t)(n0 + row) * K + k0 + cg * 8], lB);
        }
        __syncthreads();
        short8 af[4], bfr[4];
#pragma unroll
        for (int mt = 0; mt < 4; ++mt)
            af[mt] = *(const short8*)&As[(wm + mt * 16 + ln) * 32 + kq * 8];
#pragma unroll
        for (int nt = 0; nt < 4; ++nt)
            bfr[nt] = *(const short8*)&Bs[(wn + nt * 16 + ln) * 32 + kq * 8];
#pragma unroll
        for (int mt = 0; mt < 4; ++mt)
#pragma unroll
            for (int nt = 0; nt < 4; ++nt)
                acc[mt][nt] = __builtin_amdgcn_mfma_f32_16x16x32_bf16(
                    af[mt], bfr[nt], acc[mt][nt], 0, 0, 0);
        __syncthreads();
    }
    const int seg = n0 >> 10;                 // 0=Q, 1=K, 2=V (block-uniform)
    if (seg == 0) {
#pragma unroll
        for (int mt = 0; mt < 4; ++mt)
#pragma unroll
            for (int nt = 0; nt < 4; ++nt)
#pragma unroll
                for (int r = 0; r < 4; ++r) {
                    int row = m0 + wm + mt * 16 + kq * 4 + r;
                    int col = (n0 + wn + nt * 16 + ln) & 1023;
                    qo[(size_t)row * 1024 + col] = f2bf(acc[mt][nt][r] * qscale);
                }
    } else if (seg == 1) {
#pragma unroll
        for (int mt = 0; mt < 4; ++mt)
#pragma unroll
            for (int nt = 0; nt < 4; ++nt)
#pragma unroll
                for (int r = 0; r < 4; ++r) {
                    int row = m0 + wm + mt * 16 + kq * 4 + r;
                    int col = (n0 + wn + nt * 16 + ln) & 1023;
                    ko[(size_t)row * 1024 + col] = f2bf(acc[mt][nt][r]);
                }
    } else {
#pragma unroll
        for (int mt = 0; mt < 4; ++mt)
#pragma unroll
            for (int nt = 0; nt < 4; ++nt)
#pragma unroll
                for (int r = 0; r < 4; ++r) {
                    int t = m0 + wm + mt * 16 + kq * 4 + r;
                    int col = (n0 + wn + nt * 16 + ln) & 1023;
                    int b = t >> 11, n = t & 2047;
                    vo[((size_t)(b * 1024 + col)) * 2048 + n] = f2bf(acc[mt][nt][r]);
                }
    }
}

// ---------------------------------------------------------------------------
// GEMM: C[M][N] = A[M][K] @ Bt[N][K]^T, fp32 out (final projection only).
// Flat grid, XCD-local A-panel mapping (R17).
// ---------------------------------------------------------------------------
__global__ __launch_bounds__(256) void gemm_bt(
    const u16* __restrict__ A, const u16* __restrict__ Bt,
    float* __restrict__ C, int M, int N, int K) {
    __shared__ __attribute__((aligned(16))) u16 As[128 * 32];
    __shared__ __attribute__((aligned(16))) u16 Bs[128 * 32];
    const int tid = threadIdx.x;
    const int mPanels = M >> 7;
    const int bid = blockIdx.x;
    const int m0 = (bid % mPanels) * 128;
    const int n0 = (bid / mPanels) * 128;
    const int wid = tid >> 6;
    const int lane = tid & 63;
    const int ln = lane & 15, kq = lane >> 4;
    const int wm = (wid >> 1) * 64, wn = (wid & 1) * 64;

    float4v acc[4][4] = {};
    for (int k0 = 0; k0 < K; k0 += 32) {
#pragma unroll
        for (int i = 0; i < 2; ++i) {
            int chunk = tid + i * 256;          // 16B chunk id, 0..511
            int row = chunk >> 2, cg = chunk & 3;
            u16* lA = &As[(size_t)(i * 256 + wid * 64) * 8];
            u16* lB = &Bs[(size_t)(i * 256 + wid * 64) * 8];
            gld_lds16(&A[(size_t)(m0 + row) * K + k0 + cg * 8], lA);
            gld_lds16(&Bt[(size_t)(n0 + row) * K + k0 + cg * 8], lB);
        }
        __syncthreads();
        short8 af[4], bfr[4];
#pragma unroll
        for (int mt = 0; mt < 4; ++mt)
            af[mt] = *(const short8*)&As[(wm + mt * 16 + ln) * 32 + kq * 8];
#pragma unroll
        for (int nt = 0; nt < 4; ++nt)
            bfr[nt] = *(const short8*)&Bs[(wn + nt * 16 + ln) * 32 + kq * 8];
#pragma unroll
        for (int mt = 0; mt < 4; ++mt)
#pragma unroll
            for (int nt = 0; nt < 4; ++nt)
                acc[mt][nt] = __builtin_amdgcn_mfma_f32_16x16x32_bf16(
                    af[mt], bfr[nt], acc[mt][nt], 0, 0, 0);
        __syncthreads();
    }
#pragma unroll
    for (int mt = 0; mt < 4; ++mt)
#pragma unroll
        for (int nt = 0; nt < 4; ++nt)
#pragma unroll
            for (int r = 0; r < 4; ++r) {
                int row = m0 + wm + mt * 16 + kq * 4 + r;
                int col = n0 + wn + nt * 16 + ln;
                C[(size_t)row * N + col] = acc[mt][nt][r];
            }
}

// ---------------------------------------------------------------------------
// Fused attention, head-axis softmax.  R16 kernel FROZEN (best: 272us,
// absmax 0.15625).  Structure: k-tile 64, 2 barriers/window, 32 windows,
// E bf16 stride 72, 1024 thr (wave=head), 1 block/CU (register-file-forced).
//  * no fminf clamp (S*0.1803 ~ N(0,1.44^2), never near 127)
//  * loop-carried K/V base pointers
//  * Dsum u32-pair unpack
// LDS = 2*73728 (E) + 8704 (Di) = 156160 B.
// qb/cb alias -- block reads its own 32 Q rows before writing same rows.
// ---------------------------------------------------------------------------
__global__ __launch_bounds__(1024) void attn_kernel(
    const u16* qb, const u16* __restrict__ kb,
    const u16* __restrict__ vt, u16* cb) {
    // E rows = h*32+q (512), cols k 0..63 bf16, stride 72 u16 (144 B)
    __shared__ __attribute__((aligned(16))) u16   Ebuf[2][512 * 72]; // 147456 B
    __shared__ __attribute__((aligned(16))) float Di[32 * 68];       //   8704 B

    const int b = blockIdx.y;
    const int q0 = blockIdx.x * 32;
    const int tid = threadIdx.x;
    const int wid = tid >> 6, lane = tid & 63;   // wid 0..15 = head
    const int ln = lane & 15, kq = lane >> 4;
    const int h = wid;

    // Preload Q fragments (already scaled by 0.125*log2e in the Q GEMM)
    short8 aq[2][2];   // [mt][kc]
#pragma unroll
    for (int mt = 0; mt < 2; ++mt)
#pragma unroll
        for (int kc = 0; kc < 2; ++kc)
            aq[mt][kc] = *(const short8*)&qb[
                (size_t)(b * 2048 + q0 + mt * 16 + ln) * 1024 +
                h * 64 + kc * 32 + kq * 8];

    float4v cacc[2][4] = {};   // [mt][nt] ctx accumulators (32q x 64d)

    // loop-carried gather bases (advance by constant per window)
    const u16* kp = kb + (size_t)(b * 2048 + ln) * 1024 + h * 64 + kq * 8;
    const u16* vp = vt + (size_t)(b * 1024 + h * 64 + ln) * 2048 + kq * 8;

#pragma unroll 1
    for (int t = 0; t < 32; ++t) {
        u16* E = Ebuf[t & 1];

        // ---- S^T = K @ Q^T, exp2, bf16 E-store; two 32-key halves keep the
        //      live set small (aq16 + bk16 + sacc16).
#pragma unroll
        for (int c = 0; c < 2; ++c) {
            short8 bk[2][2];   // [kc][nt]
#pragma unroll
            for (int kc = 0; kc < 2; ++kc)
#pragma unroll
                for (int nt = 0; nt < 2; ++nt)
                    bk[kc][nt] = *(const short8*)&kp[
                        (size_t)(c * 32 + nt * 16) * 1024 + kc * 32];
            float4v sacc[2][2] = {};   // [mt][nt]; C: col=q=ln, row=k=kq*4+r
#pragma unroll
            for (int kc = 0; kc < 2; ++kc)
#pragma unroll
                for (int mt = 0; mt < 2; ++mt)
#pragma unroll
                    for (int nt = 0; nt < 2; ++nt)
                        sacc[mt][nt] = __builtin_amdgcn_mfma_f32_16x16x32_bf16(
                            bk[kc][nt], aq[mt][kc], sacc[mt][nt], 0, 0, 0);
#pragma unroll
            for (int mt = 0; mt < 2; ++mt)
#pragma unroll
                for (int nt = 0; nt < 2; ++nt) {
                    // no clamp: |S*0.1803| <= ~9 << 127 (overflow-safe)
                    float e0 = exp2f(sacc[mt][nt][0]);
                    float e1 = exp2f(sacc[mt][nt][1]);
                    float e2 = exp2f(sacc[mt][nt][2]);
                    float e3 = exp2f(sacc[mt][nt][3]);
                    uint2v w; w[0] = cvtpk(e0, e1); w[1] = cvtpk(e2, e3);
                    *(uint2v*)&E[(h * 32 + mt * 16 + ln) * 72 +
                                 c * 32 + nt * 16 + kq * 4] = w;
                }
        }

        // ---- hoisted V gather (consumed after BAR-B; hides global latency)
        short8 bv[2][4];   // [c][nt]
#pragma unroll
        for (int c = 0; c < 2; ++c)
#pragma unroll
            for (int nt = 0; nt < 4; ++nt)
                bv[c][nt] = *(const short8*)&vp[
                    (size_t)(nt * 16) * 2048 + c * 32];

        __syncthreads();   // BAR-A: E[cur] complete

        // ---- Dinv = 1/sum_h E: thread (q=tid>>5, kk=tid&31) owns k=2kk,2kk+1
        {
            const int q = tid >> 5, kk = tid & 31;
            const u16* ec = &E[q * 72 + 2 * kk];
            float d0 = 0.f, d1 = 0.f, d2 = 0.f, d3 = 0.f;
#pragma unroll
            for (int hh = 0; hh < 8; ++hh) {
                u32 ea = *(const u32*)&ec[(2 * hh) * (32 * 72)];
                u32 eb = *(const u32*)&ec[(2 * hh + 1) * (32 * 72)];
                d0 += bflo(ea); d1 += bfhi(ea);
                d2 += bflo(eb); d3 += bfhi(eb);
            }
            float2v dv;
            dv[0] = __builtin_amdgcn_rcpf(d0 + d2);
            dv[1] = __builtin_amdgcn_rcpf(d1 + d3);
            *(float2v*)&Di[q * 68 + 2 * kk] = dv;
        }
        __syncthreads();   // BAR-B: Di complete

        // ---- A-frag = (E * Dinv) packed bf16 via cvt_pk; ctx += A @ V
#pragma unroll
        for (int mt = 0; mt < 2; ++mt) {
            short8 ap[2];
#pragma unroll
            for (int c = 0; c < 2; ++c) {
                const u16* ep = &E[(h * 32 + mt * 16 + ln) * 72 + c * 32 + kq * 8];
                uint2v ea = *(const uint2v*)&ep[0];   // k = +0..3
                uint2v eb = *(const uint2v*)&ep[4];   // k = +4..7
                const float* dp = &Di[(mt * 16 + ln) * 68 + c * 32 + kq * 8];
                float4v g0 = *(const float4v*)&dp[0];
                float4v g1 = *(const float4v*)&dp[4];
                u32 pk[4] __attribute__((aligned(16)));
                pk[0] = cvtpk(bflo(ea[0]) * g0[0], bfhi(ea[0]) * g0[1]);
                pk[1] = cvtpk(bflo(ea[1]) * g0[2], bfhi(ea[1]) * g0[3]);
                pk[2] = cvtpk(bflo(eb[0]) * g1[0], bfhi(eb[0]) * g1[1]);
                pk[3] = cvtpk(bflo(eb[1]) * g1[2], bfhi(eb[1]) * g1[3]);
                ap[c] = *(short8*)pk;
            }
#pragma unroll
            for (int nt = 0; nt < 4; ++nt) {
                cacc[mt][nt] = __builtin_amdgcn_mfma_f32_16x16x32_bf16(
                    ap[0], bv[0][nt], cacc[mt][nt], 0, 0, 0);
                cacc[mt][nt] = __builtin_amdgcn_mfma_f32_16x16x32_bf16(
                    ap[1], bv[1][nt], cacc[mt][nt], 0, 0, 0);
            }
        }

        kp += 64 * 1024;   // next 64 keys
        vp += 64;
    }

    // Epilogue: ctx[b*2048+q][h*64+d], bf16  (cb aliases qb -- same rows only)
#pragma unroll
    for (int mt = 0; mt < 2; ++mt)
#pragma unroll
        for (int nt = 0; nt < 4; ++nt)
#pragma unroll
            for (int r = 0; r < 4; ++r) {
                int row = b * 2048 + q0 + mt * 16 + kq * 4 + r;
                int col = h * 64 + nt * 16 + ln;
                cb[(size_t)row * 1024 + col] = f2bf(cacc[mt][nt][r]);
            }
}

// ---------------------------------------------------------------------------
extern "C" void kernel_launch(void* const* d_in, const int* in_sizes, int n_in,
                              void* d_out, int out_size, void* d_ws, size_t ws_size,
                              hipStream_t stream) {
    const float* x   = (const float*)d_in[0];   // [8192][1024] fp32
    const float* w_q = (const float*)d_in[1];   // [1024][1024] fp32 (K x N)
    const float* w_k = (const float*)d_in[2];
    const float* w_v = (const float*)d_in[3];
    const float* w_o = (const float*)d_in[4];

    char* ws = (char*)d_ws;
    const size_t SZ_W   = (size_t)1024 * 1024 * 2;   // 2 MiB
    const size_t SZ_TOK = (size_t)8192 * 1024 * 2;   // 16 MiB
    // ws layout (40 MiB): x_bf | wtq wtk wtv wto | q_buf(=ctx)
    // wtq|wtk|wtv are CONTIGUOUS = one [3072][1024] Bt for the fused QKV GEMM.
    u16* x_bf  = (u16*)(ws);
    u16* wtq   = (u16*)(ws + SZ_TOK);
    u16* wtk   = (u16*)(ws + SZ_TOK + SZ_W);
    u16* wtv   = (u16*)(ws + SZ_TOK + 2 * SZ_W);
    u16* wto   = (u16*)(ws + SZ_TOK + 3 * SZ_W);
    u16* q_buf = (u16*)(ws + SZ_TOK + 4 * SZ_W);     // also ctx (aliased)
    // k_buf / vt_buf live in d_out (32 MiB fp32) -- dead before final GEMM writes it
    u16* k_buf  = (u16*)d_out;
    u16* vt_buf = (u16*)d_out + (size_t)8192 * 1024;

    // 0. convert x to bf16
    convert_x<<<4096, 256, 0, stream>>>(x, x_bf);

    // 1. transpose+convert weights to Bt (N x K) bf16 layout
    transpose_w<<<dim3(32, 32, 4), dim3(32, 8), 0, stream>>>(
        w_q, w_k, w_v, w_o, wtq, wtk, wtv, wto);

    // 2. FUSED QKV projection: one N=3072 GEMM, 1536 blocks (6/CU cap).
    //    Q pre-scaled by 0.125*log2e; V written transposed [b*1024+f][2048].
    gemm_qkv<<<dim3(1536), 256, 0, stream>>>(
        x_bf, wtq, q_buf, k_buf, vt_buf, 0.18033688f);

    // 3. fused attention with head-axis softmax (ctx written into q_buf)
    attn_kernel<<<dim3(64, 4), 1024, 0, stream>>>(q_buf, k_buf, vt_buf, q_buf);

    // 4. output projection -> fp32 d_out (overwrites k_buf/vt_buf scratch)
    gemm_bt<<<dim3(512), 256, 0, stream>>>(q_buf, wto, (float*)d_out, 8192, 1024, 1024);
}

// Round 14
// 461.987 us; speedup vs baseline: 1.0647x; 1.0647x over previous
//
#include <hip/hip_runtime.h>
#include <hip/hip_bf16.h>

typedef unsigned short u16;
typedef unsigned int u32;
typedef __attribute__((ext_vector_type(8))) short short8;   // bf16x8 MFMA frag (4 VGPR)
typedef __attribute__((ext_vector_type(4))) float float4v;  // fp32x4 acc
typedef __attribute__((ext_vector_type(4))) unsigned int uint4v; // 16B vector
typedef __attribute__((ext_vector_type(2))) unsigned int uint2v; // 8B vector
typedef __attribute__((ext_vector_type(2))) float float2v;  // 8B float pair

__device__ __forceinline__ u16 f2bf(float f) {
    union { float f; unsigned int u; } v; v.f = f;
    unsigned int r = v.u + 0x7fffu + ((v.u >> 16) & 1u);  // RNE
    return (u16)(r >> 16);
}

// packed fp32x2 -> bf16x2 (no builtin on gfx950; T12 recipe)
__device__ __forceinline__ u32 cvtpk(float lo, float hi) {
    u32 r;
    asm("v_cvt_pk_bf16_f32 %0, %1, %2" : "=v"(r) : "v"(lo), "v"(hi));
    return r;
}
// bf16 pair unpack: element 0 is low u16, element 1 is high u16
__device__ __forceinline__ float bflo(u32 u) {
    union { u32 u; float f; } v; v.u = u << 16; return v.f;
}
__device__ __forceinline__ float bfhi(u32 u) {
    union { u32 u; float f; } v; v.u = u & 0xffff0000u; return v.f;
}

// async 16B global -> LDS (lane i lands at ldsbase + i*16)
__device__ __forceinline__ void gld_lds16(const u16* g, u16* l) {
    __builtin_amdgcn_global_load_lds(
        (const __attribute__((address_space(1))) u32*)g,
        (__attribute__((address_space(3))) u32*)l, 16, 0, 0);
}

// ---------------------------------------------------------------------------
// x: fp32 [8192*1024] -> bf16. 8 elements/thread.
// ---------------------------------------------------------------------------
__global__ __launch_bounds__(256) void convert_x(
    const float* __restrict__ x, u16* __restrict__ xb) {
    int i = (blockIdx.x * 256 + threadIdx.x) * 8;
    float4v a = *(const float4v*)&x[i];
    float4v b = *(const float4v*)&x[i + 4];
    u16 tmp[8] __attribute__((aligned(16)));
#pragma unroll
    for (int j = 0; j < 4; ++j) { tmp[j] = f2bf(a[j]); tmp[4 + j] = f2bf(b[j]); }
    *(uint4v*)&xb[i] = *(uint4v*)tmp;
}

// ---------------------------------------------------------------------------
// Weight transpose+convert: W fp32 [1024][1024] (K x N) -> Wt bf16 (N x K).
// ---------------------------------------------------------------------------
__global__ __launch_bounds__(256) void transpose_w(
    const float* __restrict__ w0, const float* __restrict__ w1,
    const float* __restrict__ w2, const float* __restrict__ w3,
    u16* __restrict__ o0, u16* __restrict__ o1,
    u16* __restrict__ o2, u16* __restrict__ o3) {
    __shared__ u16 t[32][33];
    int z = blockIdx.z;
    const float* w = (z == 0) ? w0 : (z == 1) ? w1 : (z == 2) ? w2 : w3;
    u16* o         = (z == 0) ? o0 : (z == 1) ? o1 : (z == 2) ? o2 : o3;
    int bx = blockIdx.x * 32;   // input col (n)
    int by = blockIdx.y * 32;   // input row (k)
    int x = threadIdx.x, y = threadIdx.y;   // block (32,8)
#pragma unroll
    for (int i = 0; i < 4; ++i)
        t[y + i * 8][x] = f2bf(w[(size_t)(by + y + i * 8) * 1024 + bx + x]);
    __syncthreads();
#pragma unroll
    for (int i = 0; i < 4; ++i)
        o[(size_t)(bx + y + i * 8) * 1024 + by + x] = t[x][y + i * 8];
}

// ---------------------------------------------------------------------------
// GEMM: C[M][N] = A[M][K] @ Bt[N][K]^T, bf16 in, fp32 accum.
// R19: 128x64 tiles -> grid 1024 -> 4 blocks/CU (was 2 at 128x128/512).
// Evidence: R17 GEMMs ran 380 TF at 2 blocks/CU; m102's shape curve is
// nearly a pure grid-size curve (grid 1024 -> 833 TF).  Register check:
// acc[4][2]=32 AGPR + ~60 VGPR = 92 combined < 128 at 4 waves/SIMD (this
// is why GEMM blocks CAN double up where the 1024-thread attn could not).
// R18 lesson: get occupancy by smaller tiles, NOT by merging launches
// (merge thrashed L2 with 3 B-matrices -> regressed).
// XCD A-panel mapping: m = bid % 64; co-XCD invariant under +64n.
// mode 0: bf16 out, scaled by oscale; mode 1: bf16 transposed V; mode 2: fp32.
// ---------------------------------------------------------------------------
__global__ __launch_bounds__(256) void gemm_bt(
    const u16* __restrict__ A, const u16* __restrict__ Bt,
    void* __restrict__ Cout, int M, int N, int K, int mode, float oscale) {
    __shared__ __attribute__((aligned(16))) u16 As[128 * 32];   // 8 KB
    __shared__ __attribute__((aligned(16))) u16 Bs[64 * 32];    // 4 KB
    const int tid = threadIdx.x;
    const int mPanels = M >> 7;               // 64 for M=8192
    const int bid = blockIdx.x;
    const int m0 = (bid % mPanels) * 128;     // row panel: XCD-resident
    const int n0 = (bid / mPanels) * 64;      // col panel (16 panels)
    const int wid = tid >> 6;
    const int lane = tid & 63;
    const int ln = lane & 15, kq = lane >> 4;
    const int wm = (wid >> 1) * 64, wn = (wid & 1) * 32;

    float4v acc[4][2] = {};
    for (int k0 = 0; k0 < K; k0 += 32) {
        // A: 512 16B-chunks (2/thread); B: 256 chunks (1/thread)
#pragma unroll
        for (int i = 0; i < 2; ++i) {
            int chunk = tid + i * 256;          // 0..511
            int row = chunk >> 2, cg = chunk & 3;
            u16* lA = &As[(size_t)(i * 256 + wid * 64) * 8];
            gld_lds16(&A[(size_t)(m0 + row) * K + k0 + cg * 8], lA);
        }
        {
            int row = tid >> 2, cg = tid & 3;   // 0..63 rows
            u16* lB = &Bs[(size_t)(wid * 64) * 8];
            gld_lds16(&Bt[(size_t)(n0 + row) * K + k0 + cg * 8], lB);
        }
        __syncthreads();
        short8 af[4], bfr[2];
#pragma unroll
        for (int mt = 0; mt < 4; ++mt)
            af[mt] = *(const short8*)&As[(wm + mt * 16 + ln) * 32 + kq * 8];
#pragma unroll
        for (int nt = 0; nt < 2; ++nt)
            bfr[nt] = *(const short8*)&Bs[(wn + nt * 16 + ln) * 32 + kq * 8];
#pragma unroll
        for (int mt = 0; mt < 4; ++mt)
#pragma unroll
            for (int nt = 0; nt < 2; ++nt)
                acc[mt][nt] = __builtin_amdgcn_mfma_f32_16x16x32_bf16(
                    af[mt], bfr[nt], acc[mt][nt], 0, 0, 0);
        __syncthreads();
    }
    if (mode == 0) {
        u16* C = (u16*)Cout;
#pragma unroll
        for (int mt = 0; mt < 4; ++mt)
#pragma unroll
            for (int nt = 0; nt < 2; ++nt)
#pragma unroll
                for (int r = 0; r < 4; ++r) {
                    int row = m0 + wm + mt * 16 + kq * 4 + r;
                    int col = n0 + wn + nt * 16 + ln;
                    C[(size_t)row * N + col] = f2bf(acc[mt][nt][r] * oscale);
                }
    } else if (mode == 1) {
        u16* C = (u16*)Cout;
#pragma unroll
        for (int mt = 0; mt < 4; ++mt)
#pragma unroll
            for (int nt = 0; nt < 2; ++nt)
#pragma unroll
                for (int r = 0; r < 4; ++r) {
                    int t = m0 + wm + mt * 16 + kq * 4 + r;
                    int col = n0 + wn + nt * 16 + ln;
                    int b = t >> 11, n = t & 2047;
                    C[((size_t)(b * 1024 + col)) * 2048 + n] = f2bf(acc[mt][nt][r]);
                }
    } else {
        float* C = (float*)Cout;
#pragma unroll
        for (int mt = 0; mt < 4; ++mt)
#pragma unroll
            for (int nt = 0; nt < 2; ++nt)
#pragma unroll
                for (int r = 0; r < 4; ++r) {
                    int row = m0 + wm + mt * 16 + kq * 4 + r;
                    int col = n0 + wn + nt * 16 + ln;
                    C[(size_t)row * N + col] = acc[mt][nt][r];
                }
    }
}

// ---------------------------------------------------------------------------
// Fused attention, head-axis softmax.  R16 kernel FROZEN (best: 272us,
// absmax 0.15625).  Structure: k-tile 64, 2 barriers/window, 32 windows,
// E bf16 stride 72, 1024 thr (wave=head), 1 block/CU (register-file-forced).
//  * no fminf clamp (S*0.1803 ~ N(0,1.44^2), never near 127)
//  * loop-carried K/V base pointers
//  * Dsum u32-pair unpack
// LDS = 2*73728 (E) + 8704 (Di) = 156160 B.
// qb/cb alias -- block reads its own 32 Q rows before writing same rows.
// ---------------------------------------------------------------------------
__global__ __launch_bounds__(1024) void attn_kernel(
    const u16* qb, const u16* __restrict__ kb,
    const u16* __restrict__ vt, u16* cb) {
    // E rows = h*32+q (512), cols k 0..63 bf16, stride 72 u16 (144 B)
    __shared__ __attribute__((aligned(16))) u16   Ebuf[2][512 * 72]; // 147456 B
    __shared__ __attribute__((aligned(16))) float Di[32 * 68];       //   8704 B

    const int b = blockIdx.y;
    const int q0 = blockIdx.x * 32;
    const int tid = threadIdx.x;
    const int wid = tid >> 6, lane = tid & 63;   // wid 0..15 = head
    const int ln = lane & 15, kq = lane >> 4;
    const int h = wid;

    // Preload Q fragments (already scaled by 0.125*log2e in the Q GEMM)
    short8 aq[2][2];   // [mt][kc]
#pragma unroll
    for (int mt = 0; mt < 2; ++mt)
#pragma unroll
        for (int kc = 0; kc < 2; ++kc)
            aq[mt][kc] = *(const short8*)&qb[
                (size_t)(b * 2048 + q0 + mt * 16 + ln) * 1024 +
                h * 64 + kc * 32 + kq * 8];

    float4v cacc[2][4] = {};   // [mt][nt] ctx accumulators (32q x 64d)

    // loop-carried gather bases (advance by constant per window)
    const u16* kp = kb + (size_t)(b * 2048 + ln) * 1024 + h * 64 + kq * 8;
    const u16* vp = vt + (size_t)(b * 1024 + h * 64 + ln) * 2048 + kq * 8;

#pragma unroll 1
    for (int t = 0; t < 32; ++t) {
        u16* E = Ebuf[t & 1];

        // ---- S^T = K @ Q^T, exp2, bf16 E-store; two 32-key halves keep the
        //      live set small (aq16 + bk16 + sacc16).
#pragma unroll
        for (int c = 0; c < 2; ++c) {
            short8 bk[2][2];   // [kc][nt]
#pragma unroll
            for (int kc = 0; kc < 2; ++kc)
#pragma unroll
                for (int nt = 0; nt < 2; ++nt)
                    bk[kc][nt] = *(const short8*)&kp[
                        (size_t)(c * 32 + nt * 16) * 1024 + kc * 32];
            float4v sacc[2][2] = {};   // [mt][nt]; C: col=q=ln, row=k=kq*4+r
#pragma unroll
            for (int kc = 0; kc < 2; ++kc)
#pragma unroll
                for (int mt = 0; mt < 2; ++mt)
#pragma unroll
                    for (int nt = 0; nt < 2; ++nt)
                        sacc[mt][nt] = __builtin_amdgcn_mfma_f32_16x16x32_bf16(
                            bk[kc][nt], aq[mt][kc], sacc[mt][nt], 0, 0, 0);
#pragma unroll
            for (int mt = 0; mt < 2; ++mt)
#pragma unroll
                for (int nt = 0; nt < 2; ++nt) {
                    // no clamp: |S*0.1803| <= ~9 << 127 (overflow-safe)
                    float e0 = exp2f(sacc[mt][nt][0]);
                    float e1 = exp2f(sacc[mt][nt][1]);
                    float e2 = exp2f(sacc[mt][nt][2]);
                    float e3 = exp2f(sacc[mt][nt][3]);
                    uint2v w; w[0] = cvtpk(e0, e1); w[1] = cvtpk(e2, e3);
                    *(uint2v*)&E[(h * 32 + mt * 16 + ln) * 72 +
                                 c * 32 + nt * 16 + kq * 4] = w;
                }
        }

        // ---- hoisted V gather (consumed after BAR-B; hides global latency)
        short8 bv[2][4];   // [c][nt]
#pragma unroll
        for (int c = 0; c < 2; ++c)
#pragma unroll
            for (int nt = 0; nt < 4; ++nt)
                bv[c][nt] = *(const short8*)&vp[
                    (size_t)(nt * 16) * 2048 + c * 32];

        __syncthreads();   // BAR-A: E[cur] complete

        // ---- Dinv = 1/sum_h E: thread (q=tid>>5, kk=tid&31) owns k=2kk,2kk+1
        {
            const int q = tid >> 5, kk = tid & 31;
            const u16* ec = &E[q * 72 + 2 * kk];
            float d0 = 0.f, d1 = 0.f, d2 = 0.f, d3 = 0.f;
#pragma unroll
            for (int hh = 0; hh < 8; ++hh) {
                u32 ea = *(const u32*)&ec[(2 * hh) * (32 * 72)];
                u32 eb = *(const u32*)&ec[(2 * hh + 1) * (32 * 72)];
                d0 += bflo(ea); d1 += bfhi(ea);
                d2 += bflo(eb); d3 += bfhi(eb);
            }
            float2v dv;
            dv[0] = __builtin_amdgcn_rcpf(d0 + d2);
            dv[1] = __builtin_amdgcn_rcpf(d1 + d3);
            *(float2v*)&Di[q * 68 + 2 * kk] = dv;
        }
        __syncthreads();   // BAR-B: Di complete

        // ---- A-frag = (E * Dinv) packed bf16 via cvt_pk; ctx += A @ V
#pragma unroll
        for (int mt = 0; mt < 2; ++mt) {
            short8 ap[2];
#pragma unroll
            for (int c = 0; c < 2; ++c) {
                const u16* ep = &E[(h * 32 + mt * 16 + ln) * 72 + c * 32 + kq * 8];
                uint2v ea = *(const uint2v*)&ep[0];   // k = +0..3
                uint2v eb = *(const uint2v*)&ep[4];   // k = +4..7
                const float* dp = &Di[(mt * 16 + ln) * 68 + c * 32 + kq * 8];
                float4v g0 = *(const float4v*)&dp[0];
                float4v g1 = *(const float4v*)&dp[4];
                u32 pk[4] __attribute__((aligned(16)));
                pk[0] = cvtpk(bflo(ea[0]) * g0[0], bfhi(ea[0]) * g0[1]);
                pk[1] = cvtpk(bflo(ea[1]) * g0[2], bfhi(ea[1]) * g0[3]);
                pk[2] = cvtpk(bflo(eb[0]) * g1[0], bfhi(eb[0]) * g1[1]);
                pk[3] = cvtpk(bflo(eb[1]) * g1[2], bfhi(eb[1]) * g1[3]);
                ap[c] = *(short8*)pk;
            }
#pragma unroll
            for (int nt = 0; nt < 4; ++nt) {
                cacc[mt][nt] = __builtin_amdgcn_mfma_f32_16x16x32_bf16(
                    ap[0], bv[0][nt], cacc[mt][nt], 0, 0, 0);
                cacc[mt][nt] = __builtin_amdgcn_mfma_f32_16x16x32_bf16(
                    ap[1], bv[1][nt], cacc[mt][nt], 0, 0, 0);
            }
        }

        kp += 64 * 1024;   // next 64 keys
        vp += 64;
    }

    // Epilogue: ctx[b*2048+q][h*64+d], bf16  (cb aliases qb -- same rows only)
#pragma unroll
    for (int mt = 0; mt < 2; ++mt)
#pragma unroll
        for (int nt = 0; nt < 4; ++nt)
#pragma unroll
            for (int r = 0; r < 4; ++r) {
                int row = b * 2048 + q0 + mt * 16 + kq * 4 + r;
                int col = h * 64 + nt * 16 + ln;
                cb[(size_t)row * 1024 + col] = f2bf(cacc[mt][nt][r]);
            }
}

// ---------------------------------------------------------------------------
extern "C" void kernel_launch(void* const* d_in, const int* in_sizes, int n_in,
                              void* d_out, int out_size, void* d_ws, size_t ws_size,
                              hipStream_t stream) {
    const float* x   = (const float*)d_in[0];   // [8192][1024] fp32
    const float* w_q = (const float*)d_in[1];   // [1024][1024] fp32 (K x N)
    const float* w_k = (const float*)d_in[2];
    const float* w_v = (const float*)d_in[3];
    const float* w_o = (const float*)d_in[4];

    char* ws = (char*)d_ws;
    const size_t SZ_W   = (size_t)1024 * 1024 * 2;   // 2 MiB
    const size_t SZ_TOK = (size_t)8192 * 1024 * 2;   // 16 MiB
    // ws layout (40 MiB): x_bf | wtq wtk wtv wto | q_buf(=ctx)
    u16* x_bf  = (u16*)(ws);
    u16* wtq   = (u16*)(ws + SZ_TOK);
    u16* wtk   = (u16*)(ws + SZ_TOK + SZ_W);
    u16* wtv   = (u16*)(ws + SZ_TOK + 2 * SZ_W);
    u16* wto   = (u16*)(ws + SZ_TOK + 3 * SZ_W);
    u16* q_buf = (u16*)(ws + SZ_TOK + 4 * SZ_W);     // also ctx (aliased)
    // k_buf / vt_buf live in d_out (32 MiB fp32) -- dead before final GEMM writes it
    u16* k_buf  = (u16*)d_out;
    u16* vt_buf = (u16*)d_out + (size_t)8192 * 1024;

    // 0. convert x to bf16
    convert_x<<<4096, 256, 0, stream>>>(x, x_bf);

    // 1. transpose+convert weights to Bt (N x K) bf16 layout
    transpose_w<<<dim3(32, 32, 4), dim3(32, 8), 0, stream>>>(
        w_q, w_k, w_v, w_o, wtq, wtk, wtv, wto);

    // 2. QKV projections: 128x64 tiles, 1024 blocks each = 4 blocks/CU.
    //    Q pre-scaled by 0.125*log2e; V written transposed [b*1024+f][2048].
    gemm_bt<<<dim3(1024), 256, 0, stream>>>(x_bf, wtq, q_buf, 8192, 1024, 1024, 0, 0.18033688f);
    gemm_bt<<<dim3(1024), 256, 0, stream>>>(x_bf, wtk, k_buf, 8192, 1024, 1024, 0, 1.0f);
    gemm_bt<<<dim3(1024), 256, 0, stream>>>(x_bf, wtv, vt_buf, 8192, 1024, 1024, 1, 1.0f);

    // 3. fused attention with head-axis softmax (ctx written into q_buf)
    attn_kernel<<<dim3(64, 4), 1024, 0, stream>>>(q_buf, k_buf, vt_buf, q_buf);

    // 4. output projection -> fp32 d_out (overwrites k_buf/vt_buf scratch)
    gemm_bt<<<dim3(1024), 256, 0, stream>>>(q_buf, wto, d_out, 8192, 1024, 1024, 2, 1.0f);
}